// Round 8
// baseline (211.040 us; speedup 1.0000x reference)
//
#include <hip/hip_runtime.h>

// HierarchicalRouter: x[16384,2048] fp32, group_gate_w[8,2048], expert_gate_w[64,2048]
// out = concat(valid_mask[16384,64] as 0/1 float, normalized_weights[16384,64])
//
// R12 = R11 with ALL K-loop barriers removed (wave-private pipelines, counted vmcnt).
//  Key observation: in R11 wave w stages AND reads only its own w*KSB W-slice -> the
//  per-chunk __syncthreads (with its implicit s_waitcnt vmcnt(0) full drain, m97) was
//  pure overhead and serialized every chunk on the x-HBM drain. Now each wave
//  free-runs: split x(c) -> xload(c+2) -> glds(c+1) -> s_waitcnt vmcnt(14) ->
//  ds_read+MFMA(c). Counted wait (T4, never 0 mid-loop): after glds(c) completes the
//  queue holds x(c+2)[4]+glds(c+1)[10]=14. Tail peeled: chunk 14 -> vmcnt(10),
//  chunk 15 -> vmcnt(0). sched_barrier(0) fences pin each iteration's issue group so
//  the count is exact; "memory" clobber orders the ds_reads after the wait (rule #18).
//  x-register dependencies are compiler-tracked (auto counted vmcnt) - no manual wait.
//  Waves de-phase across the CU (8 waves/CU from 2 blocks) and hide each other's
//  latency; the only barriers left are the epilogue's.
//
//  Structure otherwise identical to R11 (passing, absmax 4.88e-4):
//   * 512 blocks x 256 thr (4 waves), 32 tokens/block, LDS 81920B -> 2 blocks/CU.
//   * prep presplits W (80 gates: 64 expert + 8 group + 8 pad) into f16 h/l planes
//     (v = h + l/2048), chunk-contiguous: byte = ks*10240 + g*2048 + pl*1024 +
//     slot*16 + j*2. Router stages per-wave 10KB slices via global_load_lds w=16.
//   * Wave w = ks-within-chunk; 10 ds_read_b128 feed 30 mfma_f32_16x16x32_f16/chunk.
//   * logit = accH + accC/2048 (exact split). Epilogue: 4-way K-reduce, softmax
//     8 tok/wave (proven fp32), coalesced stores.

#define NT 16384
#define NE 2048
#define NTH 256
#define NBLK 512
#define NCHUNK 16
#define KSB 10240
#define WCH 40960
#define LDS_BYTES 81920

typedef _Float16 v8h __attribute__((ext_vector_type(8)));
typedef float    v4f __attribute__((ext_vector_type(4)));

__global__ __launch_bounds__(256, 1)
void prep(const float* __restrict__ gw, const float* __restrict__ ew,
          _Float16* __restrict__ wf)
{
    const int t = blockIdx.x * 256 + threadIdx.x;   // 0..163839: one (ks,g,slot,j)
    const int j    = t & 7;
    const int sl   = (t >> 3) & 63;                 // slot = q*16 + m (A-fragment lane)
    const int rest = t >> 9;                        // 0..319
    const int g    = rest % 5;
    const int ks   = rest / 5;                      // 0..63 (32-float k-step)
    const int m = sl & 15, q = sl >> 4;
    const int gate = g * 16 + m;
    const int k = ks * 32 + q * 8 + j;
    float v = 0.f;
    if (gate < 64)      v = ew[gate * NE + k];
    else if (gate < 72) v = gw[(gate - 64) * NE + k];
    const _Float16 h = (_Float16)v;
    const int o = (((ks * 5 + g) * 2) * 64 + sl) * 8 + j;   // pl=0 plane
    wf[o]       = h;
    wf[o + 512] = (_Float16)((v - (float)h) * 2048.0f);     // pl=1 plane (+64 slots)
}

__global__ __launch_bounds__(NTH, 2)
void router(const float* __restrict__ x, const _Float16* __restrict__ wf,
            float* __restrict__ out)
{
    __shared__ __align__(16) char sm[LDS_BYTES];
    const int tid  = threadIdx.x;
    const int lane = tid & 63;
    const int w    = tid >> 6;                 // ks-within-chunk 0..3
    const int t0   = blockIdx.x * 32;

    // ---- x B-fragment sources (token = lane&15 + 16*tile, k = c*128 + w*32 + (lane>>4)*8) ----
    const float* xq0 = x + (size_t)(t0 + (lane & 15)) * NE + w * 32 + (lane >> 4) * 8;
    const float* xq1 = xq0 + (size_t)16 * NE;

    // ---- W staging: global_load_lds, 10 x 1KB wave-issues per chunk (wave-private slice) ----
    auto stage = [&](int c, int buf) {
        const char* src = (const char*)wf + (size_t)c * WCH + w * KSB + lane * 16;
        char* dst = sm + buf * WCH + w * KSB;              // wave-uniform base
        #pragma unroll
        for (int i = 0; i < 10; ++i)
            __builtin_amdgcn_global_load_lds(
                (const __attribute__((address_space(1))) char*)(src + i * 1024),
                (__attribute__((address_space(3))) char*)(dst + i * 1024),
                16, 0, 0);
    };

    auto split8 = [](const float4& a, const float4& b, v8h& h, v8h& l) {
        const float v[8] = {a.x, a.y, a.z, a.w, b.x, b.y, b.z, b.w};
        #pragma unroll
        for (int j = 0; j < 8; ++j) {
            const _Float16 hh = (_Float16)v[j];
            h[j] = hh;
            l[j] = (_Float16)((v[j] - (float)hh) * 2048.0f);
        }
    };

    v4f accH0[5], accC0[5], accH1[5], accC1[5];
    #pragma unroll
    for (int g = 0; g < 5; ++g) {
        accH0[g] = (v4f)(0.f); accC0[g] = (v4f)(0.f);
        accH1[g] = (v4f)(0.f); accC1[g] = (v4f)(0.f);
    }

    auto xload = [&](int c, float4& a0, float4& a1, float4& b0, float4& b1) {
        const float* p0 = xq0 + c * 128;
        const float* p1 = xq1 + c * 128;
        a0 = *(const float4*)(p0); a1 = *(const float4*)(p0 + 4);
        b0 = *(const float4*)(p1); b1 = *(const float4*)(p1 + 4);
    };

    auto mfma_block = [&](int P, const v8h& Bh0, const v8h& Bl0,
                          const v8h& Bh1, const v8h& Bl1) {
        const char* wb = sm + P * WCH + w * KSB + lane * 16;
        #pragma unroll
        for (int g = 0; g < 5; ++g) {
            const v8h Ah = *(const v8h*)(wb + g * 2048);
            const v8h Al = *(const v8h*)(wb + g * 2048 + 1024);
            accH0[g] = __builtin_amdgcn_mfma_f32_16x16x32_f16(Ah, Bh0, accH0[g], 0, 0, 0);
            accC0[g] = __builtin_amdgcn_mfma_f32_16x16x32_f16(Ah, Bl0, accC0[g], 0, 0, 0);
            accC0[g] = __builtin_amdgcn_mfma_f32_16x16x32_f16(Al, Bh0, accC0[g], 0, 0, 0);
            accH1[g] = __builtin_amdgcn_mfma_f32_16x16x32_f16(Ah, Bh1, accH1[g], 0, 0, 0);
            accC1[g] = __builtin_amdgcn_mfma_f32_16x16x32_f16(Ah, Bl1, accC1[g], 0, 0, 0);
            accC1[g] = __builtin_amdgcn_mfma_f32_16x16x32_f16(Al, Bh1, accC1[g], 0, 0, 0);
        }
    };

    // steady-state step for chunks 0..13: all issues present, wait = vmcnt(14)
    // (after glds(c) completes: x(c+2)[4] + glds(c+1)[10] outstanding)
    auto step = [&](int c, int P, float4& c00, float4& c01, float4& c10, float4& c11) {
        v8h Bh0, Bl0, Bh1, Bl1;
        split8(c00, c01, Bh0, Bl0);                // compiler auto-waits x(c) regs
        split8(c10, c11, Bh1, Bl1);
        xload(c + 2, c00, c01, c10, c11);          // WAR after split
        stage(c + 1, 1 - P);
        __builtin_amdgcn_sched_barrier(0);
        asm volatile("s_waitcnt vmcnt(14)" ::: "memory");   // glds(c) done
        __builtin_amdgcn_sched_barrier(0);
        mfma_block(P, Bh0, Bl0, Bh1, Bl1);
    };

    // named 2-deep x prefetch: even chunks in A, odd in B (rule #20)
    float4 xA00, xA01, xA10, xA11, xB00, xB01, xB10, xB11;

    // ---- prologue: x(0), x(1), glds(0) ----
    xload(0, xA00, xA01, xA10, xA11);
    xload(1, xB00, xB01, xB10, xB11);
    stage(0, 0);

    // ---- barrier-free K-loop: chunks 0..13 steady, 14/15 peeled ----
    #pragma unroll 1
    for (int cc = 0; cc < NCHUNK - 2; cc += 2) {
        step(cc,     0, xA00, xA01, xA10, xA11);
        step(cc + 1, 1, xB00, xB01, xB10, xB11);
    }
    {   // chunk 14 (P=0, regs A): no xload(16); stage(15); wait = vmcnt(10)
        v8h Bh0, Bl0, Bh1, Bl1;
        split8(xA00, xA01, Bh0, Bl0);
        split8(xA10, xA11, Bh1, Bl1);
        stage(15, 1);
        __builtin_amdgcn_sched_barrier(0);
        asm volatile("s_waitcnt vmcnt(10)" ::: "memory");   // glds(14) done
        __builtin_amdgcn_sched_barrier(0);
        mfma_block(0, Bh0, Bl0, Bh1, Bl1);
    }
    {   // chunk 15 (P=1, regs B): nothing left in flight after glds(15)
        v8h Bh0, Bl0, Bh1, Bl1;
        split8(xB00, xB01, Bh0, Bl0);
        split8(xB10, xB11, Bh1, Bl1);
        __builtin_amdgcn_sched_barrier(0);
        asm volatile("s_waitcnt vmcnt(0)" ::: "memory");    // glds(15) done
        __builtin_amdgcn_sched_barrier(0);
        mfma_block(1, Bh0, Bl0, Bh1, Bl1);
    }
    __syncthreads();                            // epilogue: cross-wave from here on

    // ---- exact recombine + 4-way K-reduce (across the 4 ks-waves) ----
    float part[2][5][4];
    #pragma unroll
    for (int g = 0; g < 5; ++g)
        #pragma unroll
        for (int r = 0; r < 4; ++r) {
            part[0][g][r] = accH0[g][r] + accC0[g][r] * (1.0f / 2048.0f);
            part[1][g][r] = accH1[g][r] + accC1[g][r] * (1.0f / 2048.0f);
        }

    float* red = (float*)sm;                    // [w-1][tile][g][r][lane] = 30720 B
    if (w > 0) {
        #pragma unroll
        for (int t = 0; t < 2; ++t)
            #pragma unroll
            for (int g = 0; g < 5; ++g)
                #pragma unroll
                for (int r = 0; r < 4; ++r)
                    red[((((w - 1) * 2 + t) * 5 + g) * 4 + r) * 64 + lane] = part[t][g][r];
    }
    __syncthreads();
    float* la = (float*)(sm + 30720);           // [32 tokens][84]
    if (w == 0) {
        #pragma unroll
        for (int t = 0; t < 2; ++t)
            #pragma unroll
            for (int g = 0; g < 5; ++g)
                #pragma unroll
                for (int r = 0; r < 4; ++r) {
                    const float v = part[t][g][r]
                        + red[(((0 * 2 + t) * 5 + g) * 4 + r) * 64 + lane]
                        + red[(((1 * 2 + t) * 5 + g) * 4 + r) * 64 + lane]
                        + red[(((2 * 2 + t) * 5 + g) * 4 + r) * 64 + lane];
                    const int gate  = g * 16 + (lane >> 4) * 4 + r;   // D row = gate
                    const int token = t * 16 + (lane & 15);           // D col = token
                    la[token * 84 + gate] = v;
                }
    }
    __syncthreads();

    // ---- per-token dual softmax + hierarchical mask (proven fp32), 8 tok/wave ----
    if (lane < 8) {
        const int token = w * 8 + lane;
        const float* lg = la + token * 84;      // [0..63]=experts, [64..71]=groups
        float* M  = (float*)(sm + 41472) + token * 64;
        float* Wn = (float*)(sm + 49664) + token * 64;

        float gpb[8];
        float gmax = lg[64];
        #pragma unroll
        for (int g = 1; g < 8; ++g) gmax = fmaxf(gmax, lg[64 + g]);
        float gsum = 0.f;
        #pragma unroll
        for (int g = 0; g < 8; ++g) { gpb[g] = __expf(lg[64 + g] - gmax); gsum += gpb[g]; }
        const float ginv = 1.f / gsum;

        float sel[64];
        float wsum = 0.f;
        #pragma unroll
        for (int g = 0; g < 8; ++g) {
            const float gp_ = gpb[g] * ginv;
            float emax = lg[g * 8];
            #pragma unroll
            for (int j = 1; j < 8; ++j) emax = fmaxf(emax, lg[g * 8 + j]);
            float ep[8]; float esum = 0.f;
            #pragma unroll
            for (int j = 0; j < 8; ++j) { ep[j] = __expf(lg[g * 8 + j] - emax); esum += ep[j]; }
            const float einv = 1.f / esum;
            const bool gm = gp_ >= 0.125f;
            #pragma unroll
            for (int j = 0; j < 8; ++j) {
                const float pe = ep[j] * einv;
                const bool v = gm && (pe >= 0.125f);
                const float ww = v ? gp_ * pe : 0.f;
                M[g * 8 + j] = v ? 1.f : 0.f;
                sel[g * 8 + j] = ww;
                wsum += ww;
            }
        }
        const float inv = 1.f / fmaxf(wsum, 1e-9f);
        #pragma unroll
        for (int e = 0; e < 64; ++e) Wn[e] = sel[e] * inv;
    }
    __syncthreads();

    // ---- coalesced stores: 32 tokens x 64 = 512 float4 per tensor ----
    const float4* M4 = (const float4*)(sm + 41472);
    const float4* W4 = (const float4*)(sm + 49664);
    float4* o0 = (float4*)(out + (size_t)t0 * 64);
    float4* o1 = (float4*)(out + (size_t)NT * 64 + (size_t)t0 * 64);
    o0[tid]       = M4[tid];
    o0[tid + 256] = M4[tid + 256];
    o1[tid]       = W4[tid];
    o1[tid + 256] = W4[tid + 256];
}

extern "C" void kernel_launch(void* const* d_in, const int* in_sizes, int n_in,
                              void* d_out, int out_size, void* d_ws, size_t ws_size,
                              hipStream_t stream) {
    const float* x  = (const float*)d_in[0];
    const float* gw = (const float*)d_in[1];
    const float* ew = (const float*)d_in[2];
    float* out = (float*)d_out;
    _Float16* wf = (_Float16*)d_ws;
    (void)ws_size; (void)in_sizes; (void)n_in; (void)out_size;

    prep<<<dim3(640), dim3(256), 0, stream>>>(gw, ew, wf);
    router<<<dim3(NBLK), dim3(NTH), 0, stream>>>(x, wf, out);
}